// Round 2
// baseline (992.937 us; speedup 1.0000x reference)
//
#include <hip/hip_runtime.h>
#include <hip/hip_bf16.h>
#include <math.h>

typedef __bf16 bf16_t;
typedef float f32x4 __attribute__((ext_vector_type(4)));
typedef __bf16 bf16x8 __attribute__((ext_vector_type(8)));
typedef __bf16 bf16x4 __attribute__((ext_vector_type(4)));
typedef int i32x4 __attribute__((ext_vector_type(4)));

#define SCALING 0.17677669529663687f
#define LNEPS 1e-5f

// ws layout (bytes); total = 224,002,176 (vt lives in d_out)
#define OFF_QKG   0u            // bf16 [131072][768]: q | k | gate; gate cols hold LN'd msa (bf16,
                                //   chunk-XOR-swizzled) until k_proj's gate epilogue overwrites them
#define OFF_LOG   201326592u    // f32  [8][512][512]: attn logits
#define OFF_BIAS  209715200u    // f32  [8][512][512]: pair bias
#define OFF_P     218103808u    // bf16 [8][512][512]: softmax probs
#define OFF_WT    222298112u    // bf16 [1024][256]  : [wq|wk|wv|wg]^T, K-chunk XOR-swizzled
#define OFF_WTO   222822400u    // bf16 [256][256]   : w_out^T
#define OFF_FLAG  222953472u    // int: 1 if inputs are fp32, 0 if bf16

#define GLOBAL_AS __attribute__((address_space(1)))
#define LDS_AS    __attribute__((address_space(3)))

static __device__ __forceinline__ f32x4 mfma16(bf16x8 a, bf16x8 b, f32x4 c) {
  return __builtin_amdgcn_mfma_f32_16x16x32_bf16(a, b, c, 0, 0, 0);
}

static __device__ __forceinline__ float ldf(const void* p, int i, int is32) {
  return is32 ? ((const float*)p)[i] : (float)((const bf16_t*)p)[i];
}
static __device__ __forceinline__ float scrubf(float x) {
  if (x != x) return 0.f;
  return fminf(fmaxf(x, -3.3e38f), 3.3e38f);
}

// ---------------- K-1: detect input dtype ----------------
__global__ __launch_bounds__(256) void k_detect(const unsigned short* raw, int* flag) {
  __shared__ int s;
  int t = threadIdx.x;
  if (t == 0) s = 0;
  __syncthreads();
  int local = 0;
  for (int i = 0; i < 16; i++) {
    unsigned short u = raw[t * 16 + i];
    int e = (u >> 7) & 0xFF;
    if (e >= 170) local = 1;   // |x| >= 2^43 as bf16: impossible for N(0,1) bf16 data
  }
  if (local) s = 1;
  __syncthreads();
  if (t == 0) *flag = s;
}

// ---------------- K0: transpose weights (any dtype -> bf16) ----------------
// wt_cat stores column c's K-row with 16B chunks XOR-swizzled: element k goes to
// index k ^ ((c&7)<<3). k_proj stages these tiles linearly via global_load_lds and
// reads fragments with the same XOR -> bank-conflict-free ds_read_b128.
__global__ __launch_bounds__(256) void k_transpose(
    const void* wq, const void* wk, const void* wv, const void* wg,
    const void* wout, const int* flag, bf16_t* wt_cat, bf16_t* wt_out) {
  int is32 = *flag;
  int idx = blockIdx.x * 256 + threadIdx.x;
  if (idx < 1024 * 256) {
    int c = idx >> 8, k = idx & 255;
    const void* src = (c < 256) ? wq : (c < 512) ? wk : (c < 768) ? wv : wg;
    wt_cat[c * 256 + (k ^ ((c & 7) << 3))] = (bf16_t)ldf(src, k * 256 + (c & 255), is32);
  } else {
    int i2 = idx - 1024 * 256;  // < 65536
    int c = i2 >> 8, k = i2 & 255;
    wt_out[c * 256 + k] = (bf16_t)ldf(wout, k * 256 + c, is32);
  }
}

// ---------------- K1: msa LayerNorm -> bf16, stored in qkg gate cols ----------------
// Writes LN'd msa row r (256 cols) into qkg[r*768 + 512 .. +768), with 16B chunks
// XOR-swizzled (logical chunk c8 stored at c8 ^ (r&7)) so k_proj's linear
// global_load_lds + swizzled ds_read_b128 fragment reads are conflict-free.
__global__ __launch_bounds__(256) void k_ln(
    const void* msa, const void* g, const void* b, const int* flag, bf16_t* qkg) {
  int is32 = *flag;
  int t = threadIdx.x, lane = t & 63, w = t >> 6;
  int c0 = lane * 4;
  float gv[4], bv[4];
#pragma unroll
  for (int e = 0; e < 4; e++) { gv[e] = ldf(g, c0 + e, is32); bv[e] = ldf(b, c0 + e, is32); }
  int row0 = blockIdx.x * 64 + w * 16;
  for (int rr = 0; rr < 16; rr++) {
    int r = row0 + rr;
    float x[4];
    if (is32) {
      f32x4 v = *(const f32x4*)((const float*)msa + (size_t)r * 256 + c0);
#pragma unroll
      for (int e = 0; e < 4; e++) x[e] = scrubf(v[e]);
    } else {
      bf16x4 v = *(const bf16x4*)((const bf16_t*)msa + (size_t)r * 256 + c0);
#pragma unroll
      for (int e = 0; e < 4; e++) x[e] = scrubf((float)v[e]);
    }
    float s = x[0] + x[1] + x[2] + x[3];
    float sq = x[0] * x[0] + x[1] * x[1] + x[2] * x[2] + x[3] * x[3];
#pragma unroll
    for (int o = 32; o >= 1; o >>= 1) {
      s += __shfl_xor(s, o, 64);
      sq += __shfl_xor(sq, o, 64);
    }
    float mu = s * (1.f / 256.f);
    float var = sq * (1.f / 256.f) - mu * mu;
    float rs = rsqrtf(fmaxf(var, 0.f) + LNEPS);
    bf16x4 y;
#pragma unroll
    for (int e = 0; e < 4; e++) y[e] = (bf16_t)((x[e] - mu) * rs * gv[e] + bv[e]);
    int pc = (lane >> 1) ^ (r & 7);   // physical 16B chunk within the 512B row
    *(bf16x4*)((char*)qkg + ((size_t)r * 768 + 512) * 2 + pc * 16 + (lane & 1) * 8) = y;
  }
}

// ---------------- K2: pair LN + @ w_b -> bias[h][q][k] (f32) ----------------
__global__ __launch_bounds__(256) void k_pair_bias(
    const void* pair, const void* g, const void* b,
    const void* wb, const int* flag, float* bias_ws) {
  __shared__ float wbs[128 * 8];  // wb[c][h]
  __shared__ float gs[128], bs[128];
  int is32 = *flag;
  int t = threadIdx.x;
  if (t < 128) { gs[t] = ldf(g, t, is32); bs[t] = ldf(b, t, is32); }
  for (int i = t; i < 1024; i += 256) wbs[i] = ldf(wb, i, is32);
  __syncthreads();
  int lane = t & 63, w = t >> 6;
  int j = lane & 7;        // element-group within row (16 elems each)
  int rowg = lane >> 3;    // row within pass (0..7)
  float gr[16], br[16];
#pragma unroll
  for (int e = 0; e < 16; e++) { gr[e] = gs[j * 16 + e]; br[e] = bs[j * 16 + e]; }
  int row0 = blockIdx.x * 64 + w * 16;
#pragma unroll
  for (int pass = 0; pass < 2; pass++) {
    int row = row0 + pass * 8 + rowg;
    float x[16];
    if (is32) {
#pragma unroll
      for (int i = 0; i < 4; i++) {
        f32x4 v = *(const f32x4*)((const float*)pair + (size_t)row * 128 + j * 16 + i * 4);
#pragma unroll
        for (int e = 0; e < 4; e++) x[i * 4 + e] = scrubf(v[e]);
      }
    } else {
#pragma unroll
      for (int i = 0; i < 2; i++) {
        i32x4 raw = *(const i32x4*)((const bf16_t*)pair + (size_t)row * 128 + j * 16 + i * 8);
        const bf16_t* sp = (const bf16_t*)&raw;
#pragma unroll
        for (int e = 0; e < 8; e++) x[i * 8 + e] = scrubf((float)sp[e]);
      }
    }
    float s = 0.f, sq = 0.f;
#pragma unroll
    for (int e = 0; e < 16; e++) { s += x[e]; sq += x[e] * x[e]; }
#pragma unroll
    for (int o = 1; o <= 4; o <<= 1) {
      s += __shfl_xor(s, o, 64);
      sq += __shfl_xor(sq, o, 64);
    }
    float mu = s * (1.f / 128.f);
    float var = sq * (1.f / 128.f) - mu * mu;
    float rs = rsqrtf(fmaxf(var, 0.f) + LNEPS);
    float ph[8] = {0.f, 0.f, 0.f, 0.f, 0.f, 0.f, 0.f, 0.f};
#pragma unroll
    for (int e = 0; e < 16; e++) {
      float xn = (x[e] - mu) * rs * gr[e] + br[e];
      const float* wp = wbs + (j * 16 + e) * 8;
      f32x4 w0 = *(const f32x4*)wp;
      f32x4 w1 = *(const f32x4*)(wp + 4);
#pragma unroll
      for (int hh = 0; hh < 4; hh++) { ph[hh] += xn * w0[hh]; ph[4 + hh] += xn * w1[hh]; }
    }
#pragma unroll
    for (int o = 1; o <= 4; o <<= 1) {
#pragma unroll
      for (int hh = 0; hh < 8; hh++) ph[hh] += __shfl_xor(ph[hh], o, 64);
    }
    if (j == 0) {
      int qp = row >> 9, kp = row & 511;
      float* bp = bias_ws + (size_t)qp * 512 + kp;
#pragma unroll
      for (int hh = 0; hh < 8; hh++) bp[(size_t)hh * 262144] = ph[hh];
    }
  }
}

// ---------------- K3: QKVG projection GEMM (pure bf16, pipelined) ----------------
// 1024 blocks x 512 threads, 1 block/CU. A (LN'd msa, bf16) staged once via
// global_load_lds from qkg gate cols; full-K A frags held in 128 VGPRs. B half-tiles
// (128 cols x 128 K) streamed through 3 LDS buffers with counted s_waitcnt vmcnt(N)
// + raw s_barrier (2 halves always in flight; epilogue stores never waited on:
// vmcnt(36) = 32 stores + 4 newest loads allowed, FIFO drains the needed half).
static __device__ __forceinline__ void issue_b(const bf16_t* wtc, int col0, int half,
                                               char* dst, int t) {
#pragma unroll
  for (int j = 0; j < 4; ++j) {
    int o = t * 16 + j * 8192;           // 0..32752
    int row = o >> 8, within = o & 255;  // 256 B per half-row
    const char* src = (const char*)wtc + (size_t)(col0 + row) * 512 + half * 256 + within;
    __builtin_amdgcn_global_load_lds((const GLOBAL_AS void*)src,
                                     (LDS_AS void*)(dst + o), 16, 0, 0);
  }
}

__global__ __launch_bounds__(512) void k_proj(
    const bf16_t* wt_cat, const void* bg, const int* mask, const int* flag,
    bf16_t* qkg, bf16_t* vt) {
  __shared__ __align__(16) char lds[98304];
  char* B0 = lds + 65536;            // 32KB, outside the A region
  char* B1 = lds;                    // overlaps A rows 0-63 (dead after frag load)
  char* B2 = lds + 32768;            // overlaps A rows 64-127
  int is32 = *flag;
  int t = threadIdx.x, lane = t & 63, w = t >> 6;
  int wr = w & 1, wc = w >> 1;       // wave tile: 64 rows x 32 cols per bn
  int hi = lane >> 4, cl = lane & 15;
  int row0 = blockIdx.x * 128;
  int rbase = row0 + wr * 64 + hi * 4;

  // ---- prologue scalar/vector loads FIRST so they age out of the vmcnt FIFO ----
  unsigned padbits = 0;
#pragma unroll
  for (int m = 0; m < 4; ++m)
#pragma unroll
    for (int i = 0; i < 4; ++i)
      if (mask[(rbase + m * 16 + i) & 511] == 0) padbits |= 1u << (m * 4 + i);
  float bgv[2][2];
#pragma unroll
  for (int bb = 0; bb < 2; ++bb)
#pragma unroll
    for (int n = 0; n < 2; ++n)
      bgv[bb][n] = ldf(bg, bb * 128 + wc * 32 + n * 16 + cl, is32);

  // ---- issue A tile (128 rows x 512B from qkg gate cols) + first B half ----
#pragma unroll
  for (int j = 0; j < 8; ++j) {
    int o = t * 16 + j * 8192;
    int row = o >> 9, within = o & 511;
    const char* src = (const char*)qkg + ((size_t)(row0 + row) * 768 + 512) * 2 + within;
    __builtin_amdgcn_global_load_lds((const GLOBAL_AS void*)src,
                                     (LDS_AS void*)(lds + o), 16, 0, 0);
  }
  issue_b(wt_cat, 0, 0, B0, t);                       // h0
  asm volatile("s_waitcnt vmcnt(4)" ::: "memory");    // A landed (h0 may fly)
  __builtin_amdgcn_s_barrier();
  asm volatile("" ::: "memory");

  // ---- one-shot A fragment load (swizzled chunks -> conflict-free) ----
  bf16x8 aall[8][4];
  {
    int arow = wr * 64 + cl;
    int sw = (cl & 7) << 4;
#pragma unroll
    for (int ks = 0; ks < 8; ++ks)
#pragma unroll
      for (int m = 0; m < 4; ++m)
        aall[ks][m] = *(const bf16x8*)(lds + (size_t)(arow + m * 16) * 512 +
                                       (((ks * 4 + hi) << 4) ^ sw));
  }
  asm volatile("s_waitcnt lgkmcnt(0)" ::: "memory");
  __builtin_amdgcn_sched_barrier(0);
  __builtin_amdgcn_s_barrier();                       // all frag reads done
  asm volatile("" ::: "memory");
  issue_b(wt_cat, 0, 1, B1, t);                       // h1

  int brow0 = wc * 32 + cl, brow1 = brow0 + 16;
  int sb = (brow0 & 7) << 4;                          // brow1 has same low bits
  f32x4 z = {0.f, 0.f, 0.f, 0.f};
  f32x4 acc[4][2] = {{z, z}, {z, z}, {z, z}, {z, z}};

  auto epilogue = [&](int bn) {
    int region = bn >> 1, col0 = bn << 7;
#pragma unroll
    for (int m = 0; m < 4; ++m) {
#pragma unroll
      for (int n = 0; n < 2; ++n) {
        int col = col0 + wc * 32 + n * 16 + cl;
#pragma unroll
        for (int i = 0; i < 4; ++i) {
          int r = rbase + m * 16 + i;
          bool pad = (padbits >> (m * 4 + i)) & 1;
          float v = acc[m][n][i];
          if (region == 0) {
            qkg[(size_t)r * 768 + col] = (bf16_t)(pad ? 0.f : v);
          } else if (region == 1) {
            qkg[(size_t)r * 768 + col] = (bf16_t)(pad ? 0.f : v * SCALING);
          } else if (region == 2) {
            int hd = col & 255;
            vt[((size_t)((r >> 9) * 8 + (hd >> 5)) * 32 + (hd & 31)) * 512 + (r & 511)] =
                (bf16_t)(pad ? 0.f : v);
          } else {
            float xg = v + bgv[bn & 1][n];
            qkg[(size_t)r * 768 + 512 + (col & 255)] = (bf16_t)(1.f / (1.f + __expf(-xg)));
          }
          acc[m][n][i] = 0.f;
        }
      }
    }
  };

#define PROJ_STEP(I, RB, WB, CNT) do {                                         \
    asm volatile("s_waitcnt vmcnt(" #CNT ")" ::: "memory");                    \
    __builtin_amdgcn_s_barrier();                                              \
    asm volatile("" ::: "memory");                                             \
    if ((I) < 14) issue_b(wt_cat, (((I) + 2) >> 1) << 7, ((I) + 2) & 1, WB, t);\
    {                                                                          \
      const char* rb = (RB);                                                   \
      _Pragma("unroll")                                                        \
      for (int kk = 0; kk < 4; ++kk) {                                         \
        int k8 = (kk * 4 + hi) << 4;                                           \
        bf16x8 b0 = *(const bf16x8*)(rb + brow0 * 256 + (k8 ^ sb));            \
        bf16x8 b1 = *(const bf16x8*)(rb + brow1 * 256 + (k8 ^ sb));            \
        _Pragma("unroll")                                                      \
        for (int m = 0; m < 4; ++m) {                                          \
          acc[m][0] = mfma16(aall[((I) & 1) * 4 + kk][m], b0, acc[m][0]);      \
          acc[m][1] = mfma16(aall[((I) & 1) * 4 + kk][m], b1, acc[m][1]);      \
        }                                                                      \
      }                                                                        \
    }                                                                          \
    if ((I) & 1) epilogue((I) >> 1);                                           \
  } while (0)

  PROJ_STEP(0,  B0, B2, 4);
  PROJ_STEP(1,  B1, B0, 4);
  PROJ_STEP(2,  B2, B1, 36);
  PROJ_STEP(3,  B0, B2, 36);
  PROJ_STEP(4,  B1, B0, 36);
  PROJ_STEP(5,  B2, B1, 36);
  PROJ_STEP(6,  B0, B2, 36);
  PROJ_STEP(7,  B1, B0, 36);
  PROJ_STEP(8,  B2, B1, 36);
  PROJ_STEP(9,  B0, B2, 36);
  PROJ_STEP(10, B1, B0, 36);
  PROJ_STEP(11, B2, B1, 36);
  PROJ_STEP(12, B0, B2, 36);
  PROJ_STEP(13, B1, B0, 36);
  PROJ_STEP(14, B2, B1, 36);
  PROJ_STEP(15, B0, B2, 36);
#undef PROJ_STEP
}

// ---------------- K4: logits[h][q][k] = sum_{n,d} q*k ----------------
__global__ __launch_bounds__(256) void k_logits(const bf16_t* qkg, float* logit_ws) {
  __shared__ bf16_t As[64 * 136];
  __shared__ bf16_t Bs[64 * 136];
  int t = threadIdx.x, lane = t & 63, w = t >> 6;
  // XCD-grouped decode: all 64 (qtile,ktile) blocks of a head land on one XCD,
  // ktile innermost within it -> A-tile L2 reuse actually works.
  int j = blockIdx.x;
  int jj = (j & 7) * 64 + (j >> 3);
  int ktile = jj & 7, qtile = (jj >> 3) & 7, h = jj >> 6;
  int mw = w & 1, nw = w >> 1;
  f32x4 z = {0.f, 0.f, 0.f, 0.f};
  f32x4 acc[2][2] = {{z, z}, {z, z}};
  for (int s = 0; s < 64; s++) {
    int kk0 = s * 128;
#pragma unroll
    for (int i = 0; i < 4; i++) {
      int flat = t + i * 256;  // 1024 chunks
      int r = flat >> 4, c8 = flat & 15;
      int kk = kk0 + c8 * 8;
      int n = kk >> 5, d = kk & 31;
      i32x4 va = *(const i32x4*)(qkg + ((size_t)(n * 512 + qtile * 64 + r)) * 768 + h * 32 + d);
      *(i32x4*)(As + r * 136 + c8 * 8) = va;
      i32x4 vb = *(const i32x4*)(qkg + ((size_t)(n * 512 + ktile * 64 + r)) * 768 + 256 + h * 32 + d);
      *(i32x4*)(Bs + r * 136 + c8 * 8) = vb;
    }
    __syncthreads();
#pragma unroll
    for (int kk = 0; kk < 128; kk += 32) {
      int ko = kk + (lane >> 4) * 8;
      bf16x8 a0 = *(const bf16x8*)(As + (mw * 32 + (lane & 15)) * 136 + ko);
      bf16x8 a1 = *(const bf16x8*)(As + (mw * 32 + 16 + (lane & 15)) * 136 + ko);
      bf16x8 b0 = *(const bf16x8*)(Bs + (nw * 32 + (lane & 15)) * 136 + ko);
      bf16x8 b1 = *(const bf16x8*)(Bs + (nw * 32 + 16 + (lane & 15)) * 136 + ko);
      acc[0][0] = mfma16(a0, b0, acc[0][0]);
      acc[0][1] = mfma16(a0, b1, acc[0][1]);
      acc[1][0] = mfma16(a1, b0, acc[1][0]);
      acc[1][1] = mfma16(a1, b1, acc[1][1]);
    }
    __syncthreads();
  }
  int quad = lane >> 4, cl = lane & 15;
#pragma unroll
  for (int mt = 0; mt < 2; mt++) {
#pragma unroll
    for (int nt = 0; nt < 2; nt++) {
      int kp = ktile * 64 + nw * 32 + nt * 16 + cl;
#pragma unroll
      for (int i = 0; i < 4; i++) {
        int q = qtile * 64 + mw * 32 + mt * 16 + quad * 4 + i;
        logit_ws[((size_t)(h * 512 + q)) * 512 + kp] = acc[mt][nt][i];
      }
    }
  }
}

// ---------------- K5: softmax over k with bias + 2D mask ----------------
__global__ __launch_bounds__(256) void k_softmax(
    const float* logit_ws, const float* bias_ws, const int* mask, bf16_t* p_ws) {
  __shared__ float red[8];
  int t = threadIdx.x;
  int hq = blockIdx.x;  // h*512 + q
  int q = hq & 511;
  bool padq = (mask[q] == 0);
  const float* lg = logit_ws + (size_t)hq * 512;
  const float* bi = bias_ws + (size_t)(hq >> 9) * 262144 + (size_t)q * 512;
  int k0 = t * 2;
  float v0 = lg[k0] + bi[k0];
  float v1 = lg[k0 + 1] + bi[k0 + 1];
  if (padq || mask[k0] == 0) v0 = -1e9f;
  if (padq || mask[k0 + 1] == 0) v1 = -1e9f;
  float m = fmaxf(v0, v1);
#pragma unroll
  for (int o = 32; o >= 1; o >>= 1) m = fmaxf(m, __shfl_xor(m, o, 64));
  if ((t & 63) == 0) red[t >> 6] = m;
  __syncthreads();
  m = fmaxf(fmaxf(red[0], red[1]), fmaxf(red[2], red[3]));
  float e0 = __expf(v0 - m), e1 = __expf(v1 - m);
  float s = e0 + e1;
#pragma unroll
  for (int o = 32; o >= 1; o >>= 1) s += __shfl_xor(s, o, 64);
  if ((t & 63) == 0) red[4 + (t >> 6)] = s;
  __syncthreads();
  s = red[4] + red[5] + red[6] + red[7];
  float inv = 1.f / s;
  p_ws[(size_t)hq * 512 + k0] = (bf16_t)(e0 * inv);
  p_ws[(size_t)hq * 512 + k0 + 1] = (bf16_t)(e1 * inv);
}

// ---------------- K6: O = P @ V, * gate -> q-region of qkg ----------------
__global__ __launch_bounds__(256) void k_av(
    const bf16_t* p_ws, const bf16_t* vt, bf16_t* qkg) {
  __shared__ bf16_t Ps[64 * 136];
  __shared__ bf16_t Vs[32 * 136];
  int t = threadIdx.x, lane = t & 63, w = t >> 6;
  // XCD-grouped decode: one head per XCD, qt innermost -> V-tile reused 8x in
  // that XCD's L2 instead of refetched; P[h] (512KB) stays L2-resident.
  int j = blockIdx.x;
  int jj = (j & 7) * 2048 + (j >> 3);
  int qt = jj & 7;
  int n = (jj >> 3) & 255;
  int h = jj >> 11;
  f32x4 z = {0.f, 0.f, 0.f, 0.f};
  f32x4 acc[2] = {z, z};
  for (int s = 0; s < 4; s++) {
    int k0 = s * 128;
#pragma unroll
    for (int i = 0; i < 4; i++) {
      int flat = t + i * 256;
      int r = flat >> 4, c8 = flat & 15;
      *(i32x4*)(Ps + r * 136 + c8 * 8) =
          *(const i32x4*)(p_ws + ((size_t)(h * 512 + qt * 64 + r)) * 512 + k0 + c8 * 8);
    }
#pragma unroll
    for (int i = 0; i < 2; i++) {
      int flat = t + i * 256;
      int r = flat >> 4, c8 = flat & 15;  // r = d
      *(i32x4*)(Vs + r * 136 + c8 * 8) =
          *(const i32x4*)(vt + ((size_t)((n * 8 + h) * 32 + r)) * 512 + k0 + c8 * 8);
    }
    __syncthreads();
#pragma unroll
    for (int kk = 0; kk < 128; kk += 32) {
      int ko = kk + (lane >> 4) * 8;
      bf16x8 a = *(const bf16x8*)(Ps + (w * 16 + (lane & 15)) * 136 + ko);
      bf16x8 b0 = *(const bf16x8*)(Vs + ((lane & 15)) * 136 + ko);
      bf16x8 b1 = *(const bf16x8*)(Vs + (16 + (lane & 15)) * 136 + ko);
      acc[0] = mfma16(a, b0, acc[0]);
      acc[1] = mfma16(a, b1, acc[1]);
    }
    __syncthreads();
  }
  int quad = lane >> 4, cl = lane & 15;
#pragma unroll
  for (int nt = 0; nt < 2; nt++) {
#pragma unroll
    for (int i = 0; i < 4; i++) {
      int q = qt * 64 + w * 16 + quad * 4 + i;
      int d = nt * 16 + cl;
      size_t base = ((size_t)(n * 512 + q)) * 768;
      float gate = (float)qkg[base + 512 + h * 32 + d];
      qkg[base + h * 32 + d] = (bf16_t)(acc[nt][i] * gate);
    }
  }
}

// ---------------- K7: out = gated @ w_out + b_out, pad-zeroed ----------------
__global__ __launch_bounds__(256) void k_out(
    const bf16_t* qkg, const bf16_t* wt_out, const void* b_out,
    const int* mask, const int* flag, void* outp) {
  __shared__ bf16_t As[64 * 72];
  __shared__ bf16_t Bs[64 * 72];
  int is32 = *flag;
  int t = threadIdx.x, lane = t & 63, w = t >> 6;
  int bm = blockIdx.x >> 2, bn = blockIdx.x & 3;
  int row0 = bm * 64;
  int mw = w & 1, nw = w >> 1;
  f32x4 z = {0.f, 0.f, 0.f, 0.f};
  f32x4 acc[2][2] = {{z, z}, {z, z}};
  for (int kt = 0; kt < 4; kt++) {
#pragma unroll
    for (int i = 0; i < 2; i++) {
      int flat = t + i * 256;
      int r = flat >> 3, c8 = flat & 7;
      *(i32x4*)(As + r * 72 + c8 * 8) =
          *(const i32x4*)(qkg + (size_t)(row0 + r) * 768 + kt * 64 + c8 * 8);
      *(i32x4*)(Bs + r * 72 + c8 * 8) =
          *(const i32x4*)(wt_out + (size_t)(bn * 64 + r) * 256 + kt * 64 + c8 * 8);
    }
    __syncthreads();
#pragma unroll
    for (int kk = 0; kk < 64; kk += 32) {
      int ko = kk + (lane >> 4) * 8;
      bf16x8 a0 = *(const bf16x8*)(As + (mw * 32 + (lane & 15)) * 72 + ko);
      bf16x8 a1 = *(const bf16x8*)(As + (mw * 32 + 16 + (lane & 15)) * 72 + ko);
      bf16x8 b0 = *(const bf16x8*)(Bs + (nw * 32 + (lane & 15)) * 72 + ko);
      bf16x8 b1 = *(const bf16x8*)(Bs + (nw * 32 + 16 + (lane & 15)) * 72 + ko);
      acc[0][0] = mfma16(a0, b0, acc[0][0]);
      acc[0][1] = mfma16(a0, b1, acc[0][1]);
      acc[1][0] = mfma16(a1, b0, acc[1][0]);
      acc[1][1] = mfma16(a1, b1, acc[1][1]);
    }
    __syncthreads();
  }
  int quad = lane >> 4, cl = lane & 15;
#pragma unroll
  for (int mt = 0; mt < 2; mt++) {
#pragma unroll
    for (int nt = 0; nt < 2; nt++) {
      int col = bn * 64 + nw * 32 + nt * 16 + cl;
      float bo = ldf(b_out, col, is32);
#pragma unroll
      for (int i = 0; i < 4; i++) {
        int r = row0 + mw * 32 + mt * 16 + quad * 4 + i;
        int l = r & 511;
        float v = acc[mt][nt][i] + bo;
        if (mask[l] == 0) v = 0.f;
        if (is32) ((float*)outp)[(size_t)r * 256 + col] = v;
        else ((bf16_t*)outp)[(size_t)r * 256 + col] = (bf16_t)v;
      }
    }
  }
}

extern "C" void kernel_launch(void* const* d_in, const int* in_sizes, int n_in,
                              void* d_out, int out_size, void* d_ws, size_t ws_size,
                              hipStream_t stream) {
  const void* msa      = d_in[0];
  const void* pair     = d_in[1];
  const void* ln_msa_g = d_in[2];
  const void* ln_msa_b = d_in[3];
  const void* ln_pair_g= d_in[4];
  const void* ln_pair_b= d_in[5];
  const void* w_q      = d_in[6];
  const void* w_k      = d_in[7];
  const void* w_v      = d_in[8];
  const void* w_b      = d_in[9];
  const void* w_g      = d_in[10];
  const void* b_g      = d_in[11];
  const void* w_out    = d_in[12];
  const void* b_out    = d_in[13];
  const int*  mask     = (const int*)d_in[14];

  char* ws = (char*)d_ws;
  bf16_t* qkg   = (bf16_t*)(ws + OFF_QKG);
  float*  logit = (float*)(ws + OFF_LOG);
  float*  biasb = (float*)(ws + OFF_BIAS);
  bf16_t* pbuf  = (bf16_t*)(ws + OFF_P);
  bf16_t* wtc   = (bf16_t*)(ws + OFF_WT);
  bf16_t* wto   = (bf16_t*)(ws + OFF_WTO);
  int*    flag  = (int*)(ws + OFF_FLAG);
  bf16_t* vt    = (bf16_t*)d_out;  // dead before k_out writes final output

  k_detect<<<1, 256, 0, stream>>>((const unsigned short*)msa, flag);
  k_transpose<<<1280, 256, 0, stream>>>(w_q, w_k, w_v, w_g, w_out, flag, wtc, wto);
  k_ln<<<2048, 256, 0, stream>>>(msa, ln_msa_g, ln_msa_b, flag, qkg);
  k_pair_bias<<<4096, 256, 0, stream>>>(pair, ln_pair_g, ln_pair_b, w_b, flag, biasb);
  k_proj<<<1024, 512, 0, stream>>>(wtc, b_g, mask, flag, qkg, vt);
  k_logits<<<512, 256, 0, stream>>>(qkg, logit);
  k_softmax<<<4096, 256, 0, stream>>>(logit, biasb, mask, pbuf);
  k_av<<<16384, 256, 0, stream>>>(pbuf, vt, qkg);
  k_out<<<8192, 256, 0, stream>>>(qkg, wto, b_out, mask, flag, d_out);
}

// Round 3
// 790.766 us; speedup vs baseline: 1.2557x; 1.2557x over previous
//
#include <hip/hip_runtime.h>
#include <hip/hip_bf16.h>
#include <math.h>

typedef __bf16 bf16_t;
typedef float f32x4 __attribute__((ext_vector_type(4)));
typedef __bf16 bf16x8 __attribute__((ext_vector_type(8)));
typedef __bf16 bf16x4 __attribute__((ext_vector_type(4)));
typedef int i32x4 __attribute__((ext_vector_type(4)));

#define SCALING 0.17677669529663687f
#define LNEPS 1e-5f

// ws layout (bytes); total = 224,002,176 (vt + msa_ln live in d_out)
#define OFF_QKG   0u            // bf16 [131072][768]: q | k | gate
#define OFF_LOG   201326592u    // f32  [8][512][512]: attn logits
#define OFF_BIAS  209715200u    // f32  [8][512][512]: pair bias
#define OFF_P     218103808u    // bf16 [8][512][512]: softmax probs
#define OFF_WT    222298112u    // bf16 [1024][256]  : [wq|wk|wv|wg]^T, K-chunk XOR-swizzled
#define OFF_WTO   222822400u    // bf16 [256][256]   : w_out^T
#define OFF_FLAG  222953472u    // int: 1 if inputs are fp32, 0 if bf16

#define GLOBAL_AS __attribute__((address_space(1)))
#define LDS_AS    __attribute__((address_space(3)))

static __device__ __forceinline__ f32x4 mfma16(bf16x8 a, bf16x8 b, f32x4 c) {
  return __builtin_amdgcn_mfma_f32_16x16x32_bf16(a, b, c, 0, 0, 0);
}

static __device__ __forceinline__ float ldf(const void* p, int i, int is32) {
  return is32 ? ((const float*)p)[i] : (float)((const bf16_t*)p)[i];
}
static __device__ __forceinline__ float scrubf(float x) {
  if (x != x) return 0.f;
  return fminf(fmaxf(x, -3.3e38f), 3.3e38f);
}

// ---------------- K-1: detect input dtype ----------------
__global__ __launch_bounds__(256) void k_detect(const unsigned short* raw, int* flag) {
  __shared__ int s;
  int t = threadIdx.x;
  if (t == 0) s = 0;
  __syncthreads();
  int local = 0;
  for (int i = 0; i < 16; i++) {
    unsigned short u = raw[t * 16 + i];
    int e = (u >> 7) & 0xFF;
    if (e >= 170) local = 1;   // |x| >= 2^43 as bf16: impossible for N(0,1) bf16 data
  }
  if (local) s = 1;
  __syncthreads();
  if (t == 0) *flag = s;
}

// ---------------- K0: transpose weights (any dtype -> bf16) ----------------
// wt_cat: column c's K-row with 16B chunks XOR-swizzled (element k at k ^ ((c&7)<<3))
// so k_proj stages linearly via global_load_lds and reads fragments conflict-free.
__global__ __launch_bounds__(256) void k_transpose(
    const void* wq, const void* wk, const void* wv, const void* wg,
    const void* wout, const int* flag, bf16_t* wt_cat, bf16_t* wt_out) {
  int is32 = *flag;
  int idx = blockIdx.x * 256 + threadIdx.x;
  if (idx < 1024 * 256) {
    int c = idx >> 8, k = idx & 255;
    const void* src = (c < 256) ? wq : (c < 512) ? wk : (c < 768) ? wv : wg;
    wt_cat[c * 256 + (k ^ ((c & 7) << 3))] = (bf16_t)ldf(src, k * 256 + (c & 255), is32);
  } else {
    int i2 = idx - 1024 * 256;  // < 65536
    int c = i2 >> 8, k = i2 & 255;
    wt_out[c * 256 + k] = (bf16_t)ldf(wout, k * 256 + c, is32);
  }
}

// ---------------- K1: msa LayerNorm -> bf16 (dense, chunk-XOR-swizzled) ----------------
// fp32 inputs: dense [131072][256] bf16 in d_out upper half (row stride 512B).
// bf16 inputs (out buffer too small): into qkg k-region (row stride 1536B, +512 off).
// 16B chunk c stored at c ^ (r&7) within each 512B row payload.
__global__ __launch_bounds__(256) void k_ln(
    const void* msa, const void* g, const void* b, const int* flag,
    char* msaln, char* qkg_bytes) {
  int is32 = *flag;
  int t = threadIdx.x, lane = t & 63, w = t >> 6;
  int c0 = lane * 4;
  float gv[4], bv[4];
#pragma unroll
  for (int e = 0; e < 4; e++) { gv[e] = ldf(g, c0 + e, is32); bv[e] = ldf(b, c0 + e, is32); }
  int row0 = blockIdx.x * 64 + w * 16;
  for (int rr = 0; rr < 16; rr++) {
    int r = row0 + rr;
    float x[4];
    if (is32) {
      f32x4 v = *(const f32x4*)((const float*)msa + (size_t)r * 256 + c0);
#pragma unroll
      for (int e = 0; e < 4; e++) x[e] = scrubf(v[e]);
    } else {
      bf16x4 v = *(const bf16x4*)((const bf16_t*)msa + (size_t)r * 256 + c0);
#pragma unroll
      for (int e = 0; e < 4; e++) x[e] = scrubf((float)v[e]);
    }
    float s = x[0] + x[1] + x[2] + x[3];
    float sq = x[0] * x[0] + x[1] * x[1] + x[2] * x[2] + x[3] * x[3];
#pragma unroll
    for (int o = 32; o >= 1; o >>= 1) {
      s += __shfl_xor(s, o, 64);
      sq += __shfl_xor(sq, o, 64);
    }
    float mu = s * (1.f / 256.f);
    float var = sq * (1.f / 256.f) - mu * mu;
    float rs = rsqrtf(fmaxf(var, 0.f) + LNEPS);
    bf16x4 y;
#pragma unroll
    for (int e = 0; e < 4; e++) y[e] = (bf16_t)((x[e] - mu) * rs * gv[e] + bv[e]);
    int pc = (lane >> 1) ^ (r & 7);   // physical 16B chunk within 512B payload
    char* dst = is32 ? (msaln + (size_t)r * 512)
                     : (qkg_bytes + (size_t)r * 1536 + 512);
    *(bf16x4*)(dst + pc * 16 + (lane & 1) * 8) = y;
  }
}

// ---------------- K2: pair LN + @ w_b -> bias[h][q][k] (f32) ----------------
__global__ __launch_bounds__(256) void k_pair_bias(
    const void* pair, const void* g, const void* b,
    const void* wb, const int* flag, float* bias_ws) {
  __shared__ float wbs[128 * 8];  // wb[c][h]
  __shared__ float gs[128], bs[128];
  int is32 = *flag;
  int t = threadIdx.x;
  if (t < 128) { gs[t] = ldf(g, t, is32); bs[t] = ldf(b, t, is32); }
  for (int i = t; i < 1024; i += 256) wbs[i] = ldf(wb, i, is32);
  __syncthreads();
  int lane = t & 63, w = t >> 6;
  int j = lane & 7;        // element-group within row (16 elems each)
  int rowg = lane >> 3;    // row within pass (0..7)
  float gr[16], br[16];
#pragma unroll
  for (int e = 0; e < 16; e++) { gr[e] = gs[j * 16 + e]; br[e] = bs[j * 16 + e]; }
  int row0 = blockIdx.x * 64 + w * 16;
#pragma unroll
  for (int pass = 0; pass < 2; pass++) {
    int row = row0 + pass * 8 + rowg;
    float x[16];
    if (is32) {
#pragma unroll
      for (int i = 0; i < 4; i++) {
        f32x4 v = *(const f32x4*)((const float*)pair + (size_t)row * 128 + j * 16 + i * 4);
#pragma unroll
        for (int e = 0; e < 4; e++) x[i * 4 + e] = scrubf(v[e]);
      }
    } else {
#pragma unroll
      for (int i = 0; i < 2; i++) {
        i32x4 raw = *(const i32x4*)((const bf16_t*)pair + (size_t)row * 128 + j * 16 + i * 8);
        const bf16_t* sp = (const bf16_t*)&raw;
#pragma unroll
        for (int e = 0; e < 8; e++) x[i * 8 + e] = scrubf((float)sp[e]);
      }
    }
    float s = 0.f, sq = 0.f;
#pragma unroll
    for (int e = 0; e < 16; e++) { s += x[e]; sq += x[e] * x[e]; }
#pragma unroll
    for (int o = 1; o <= 4; o <<= 1) {
      s += __shfl_xor(s, o, 64);
      sq += __shfl_xor(sq, o, 64);
    }
    float mu = s * (1.f / 128.f);
    float var = sq * (1.f / 128.f) - mu * mu;
    float rs = rsqrtf(fmaxf(var, 0.f) + LNEPS);
    float ph[8] = {0.f, 0.f, 0.f, 0.f, 0.f, 0.f, 0.f, 0.f};
#pragma unroll
    for (int e = 0; e < 16; e++) {
      float xn = (x[e] - mu) * rs * gr[e] + br[e];
      const float* wp = wbs + (j * 16 + e) * 8;
      f32x4 w0 = *(const f32x4*)wp;
      f32x4 w1 = *(const f32x4*)(wp + 4);
#pragma unroll
      for (int hh = 0; hh < 4; hh++) { ph[hh] += xn * w0[hh]; ph[4 + hh] += xn * w1[hh]; }
    }
#pragma unroll
    for (int o = 1; o <= 4; o <<= 1) {
#pragma unroll
      for (int hh = 0; hh < 8; hh++) ph[hh] += __shfl_xor(ph[hh], o, 64);
    }
    if (j == 0) {
      int qp = row >> 9, kp = row & 511;
      float* bp = bias_ws + (size_t)qp * 512 + kp;
#pragma unroll
      for (int hh = 0; hh < 8; hh++) bp[(size_t)hh * 262144] = ph[hh];
    }
  }
}

// ---------------- K3: QKVG projection GEMM ----------------
// 2048 blocks x 256 threads (64-row tiles), LDS = exactly 64KB -> 2 blocks/CU so
// one block's barrier drains hide under the other's compute. A (pre-LN'd bf16)
// staged once via global_load_lds, hoisted to 128 VGPRs; B half-tiles (128 cols x
// 128 K) double-buffered with __syncthreads (round-1's proven traffic behavior).
static __device__ __forceinline__ void issue_b(const bf16_t* wtc, int col0, int half,
                                               char* dst, int t) {
#pragma unroll
  for (int j = 0; j < 8; ++j) {
    int o = t * 16 + j * 4096;           // 0..32752
    int row = o >> 8, within = o & 255;  // 256 B per half-row
    const char* src = (const char*)wtc + (size_t)(col0 + row) * 512 + half * 256 + within;
    __builtin_amdgcn_global_load_lds((const GLOBAL_AS void*)src,
                                     (LDS_AS void*)(dst + o), 16, 0, 0);
  }
}

__global__ __launch_bounds__(256, 2) void k_proj(
    const bf16_t* wt_cat, const void* bg, const int* mask, const int* flag,
    const char* msaln, bf16_t* qkg, bf16_t* vt) {
  __shared__ __align__(16) char lds[65536];
  char* B0 = lds + 32768;            // B half-tile [128 cols][128 K] bf16 = 32KB
  char* B1 = lds;                    // overlaps A region (dead after frag hoist)
  int is32 = *flag;
  int t = threadIdx.x, lane = t & 63, wc = t >> 6;   // 4 waves; wave = 64 rows x 32 cols
  int hi = lane >> 4, cl = lane & 15;
  int row0 = blockIdx.x * 64;
  int rbase = row0 + hi * 4;

  // prologue scalar loads
  unsigned padbits = 0;
#pragma unroll
  for (int m = 0; m < 4; ++m)
#pragma unroll
    for (int i = 0; i < 4; ++i)
      if (mask[(rbase + m * 16 + i) & 511] == 0) padbits |= 1u << (m * 4 + i);
  float bgv[2][2];
#pragma unroll
  for (int bb = 0; bb < 2; ++bb)
#pragma unroll
    for (int n = 0; n < 2; ++n)
      bgv[bb][n] = ldf(bg, bb * 128 + wc * 32 + n * 16 + cl, is32);

  // stage A tile (64 rows x 512B, pre-LN'd bf16, chunk-swizzled at source)
  {
    const char* abase = is32 ? msaln : ((const char*)qkg + 512);
    size_t astride = is32 ? 512 : 1536;
#pragma unroll
    for (int j = 0; j < 8; ++j) {
      int o = t * 16 + j * 4096;
      int row = o >> 9, within = o & 511;
      const char* src = abase + (size_t)(row0 + row) * astride + within;
      __builtin_amdgcn_global_load_lds((const GLOBAL_AS void*)src,
                                       (LDS_AS void*)(lds + o), 16, 0, 0);
    }
  }
  issue_b(wt_cat, 0, 0, B0, t);      // bn0 half0
  __syncthreads();                   // A + h0 landed

  // one-shot A fragment hoist (swizzled chunks -> conflict-free ds_read_b128)
  bf16x8 aall[8][4];
#pragma unroll
  for (int ks = 0; ks < 8; ++ks)
#pragma unroll
    for (int m = 0; m < 4; ++m)
      aall[ks][m] = *(const bf16x8*)(lds + (size_t)(cl + m * 16) * 512 +
                                     (((ks * 4 + hi) ^ (cl & 7)) << 4));
  __syncthreads();                   // all frag reads done; B1 region free

  int brow0 = wc * 32 + cl, brow1 = brow0 + 16;
  int sb = (cl & 7) << 4;
  f32x4 z = {0.f, 0.f, 0.f, 0.f};
  f32x4 acc[4][2] = {{z, z}, {z, z}, {z, z}, {z, z}};

  for (int bn = 0; bn < 8; ++bn) {
    issue_b(wt_cat, bn << 7, 1, B1, t);   // this bn's half1
#pragma unroll
    for (int kk = 0; kk < 4; ++kk) {      // half0 from B0 (ks 0..3)
      int k8 = (kk * 4 + hi) << 4;
      bf16x8 b0 = *(const bf16x8*)(B0 + brow0 * 256 + (k8 ^ sb));
      bf16x8 b1 = *(const bf16x8*)(B0 + brow1 * 256 + (k8 ^ sb));
#pragma unroll
      for (int m = 0; m < 4; ++m) {
        acc[m][0] = mfma16(aall[kk][m], b0, acc[m][0]);
        acc[m][1] = mfma16(aall[kk][m], b1, acc[m][1]);
      }
    }
    __syncthreads();                      // h1 landed; B0 free
    if (bn < 7) issue_b(wt_cat, (bn + 1) << 7, 0, B0, t);  // next bn's half0
#pragma unroll
    for (int kk = 0; kk < 4; ++kk) {      // half1 from B1 (ks 4..7)
      int k8 = (kk * 4 + hi) << 4;
      bf16x8 b0 = *(const bf16x8*)(B1 + brow0 * 256 + (k8 ^ sb));
      bf16x8 b1 = *(const bf16x8*)(B1 + brow1 * 256 + (k8 ^ sb));
#pragma unroll
      for (int m = 0; m < 4; ++m) {
        acc[m][0] = mfma16(aall[4 + kk][m], b0, acc[m][0]);
        acc[m][1] = mfma16(aall[4 + kk][m], b1, acc[m][1]);
      }
    }
    __syncthreads();                      // next h0 landed; B1 free
    // epilogue for bn (stores drain under next bn's work until its barrier)
    int region = bn >> 1, col0 = bn << 7;
    if (region == 2) {
      // vt: pack 4 consecutive l into one 8B store
#pragma unroll
      for (int m = 0; m < 4; ++m) {
#pragma unroll
        for (int n = 0; n < 2; ++n) {
          int col = col0 + wc * 32 + n * 16 + cl;
          int hd = col & 255;
          int rb = rbase + m * 16;
          bf16x4 y;
#pragma unroll
          for (int i = 0; i < 4; ++i)
            y[i] = (bf16_t)(((padbits >> (m * 4 + i)) & 1) ? 0.f : acc[m][n][i]);
          *(bf16x4*)(vt + ((size_t)((rb >> 9) * 8 + (hd >> 5)) * 32 + (hd & 31)) * 512 +
                     (rb & 511)) = y;
          acc[m][n] = z;
        }
      }
    } else {
#pragma unroll
      for (int m = 0; m < 4; ++m) {
#pragma unroll
        for (int n = 0; n < 2; ++n) {
          int col = col0 + wc * 32 + n * 16 + cl;
#pragma unroll
          for (int i = 0; i < 4; ++i) {
            int r = rbase + m * 16 + i;
            bool pad = (padbits >> (m * 4 + i)) & 1;
            float v = acc[m][n][i];
            if (region == 0) {
              qkg[(size_t)r * 768 + col] = (bf16_t)(pad ? 0.f : v);
            } else if (region == 1) {
              qkg[(size_t)r * 768 + col] = (bf16_t)(pad ? 0.f : v * SCALING);
            } else {
              float xg = v + bgv[bn & 1][n];
              qkg[(size_t)r * 768 + 512 + (col & 255)] = (bf16_t)(1.f / (1.f + __expf(-xg)));
            }
          }
          acc[m][n] = z;
        }
      }
    }
  }
}

// ---------------- K4: logits[h][q][k] = sum_{n,d} q*k ----------------
__global__ __launch_bounds__(256) void k_logits(const bf16_t* qkg, float* logit_ws) {
  __shared__ bf16_t As[64 * 136];
  __shared__ bf16_t Bs[64 * 136];
  int t = threadIdx.x, lane = t & 63, w = t >> 6;
  // XCD-grouped decode: all 64 (qtile,ktile) blocks of a head land on one XCD.
  int j = blockIdx.x;
  int jj = (j & 7) * 64 + (j >> 3);
  int ktile = jj & 7, qtile = (jj >> 3) & 7, h = jj >> 6;
  int mw = w & 1, nw = w >> 1;
  f32x4 z = {0.f, 0.f, 0.f, 0.f};
  f32x4 acc[2][2] = {{z, z}, {z, z}};
  for (int s = 0; s < 64; s++) {
    int kk0 = s * 128;
#pragma unroll
    for (int i = 0; i < 4; i++) {
      int flat = t + i * 256;  // 1024 chunks
      int r = flat >> 4, c8 = flat & 15;
      int kk = kk0 + c8 * 8;
      int n = kk >> 5, d = kk & 31;
      i32x4 va = *(const i32x4*)(qkg + ((size_t)(n * 512 + qtile * 64 + r)) * 768 + h * 32 + d);
      *(i32x4*)(As + r * 136 + c8 * 8) = va;
      i32x4 vb = *(const i32x4*)(qkg + ((size_t)(n * 512 + ktile * 64 + r)) * 768 + 256 + h * 32 + d);
      *(i32x4*)(Bs + r * 136 + c8 * 8) = vb;
    }
    __syncthreads();
#pragma unroll
    for (int kk = 0; kk < 128; kk += 32) {
      int ko = kk + (lane >> 4) * 8;
      bf16x8 a0 = *(const bf16x8*)(As + (mw * 32 + (lane & 15)) * 136 + ko);
      bf16x8 a1 = *(const bf16x8*)(As + (mw * 32 + 16 + (lane & 15)) * 136 + ko);
      bf16x8 b0 = *(const bf16x8*)(Bs + (nw * 32 + (lane & 15)) * 136 + ko);
      bf16x8 b1 = *(const bf16x8*)(Bs + (nw * 32 + 16 + (lane & 15)) * 136 + ko);
      acc[0][0] = mfma16(a0, b0, acc[0][0]);
      acc[0][1] = mfma16(a0, b1, acc[0][1]);
      acc[1][0] = mfma16(a1, b0, acc[1][0]);
      acc[1][1] = mfma16(a1, b1, acc[1][1]);
    }
    __syncthreads();
  }
  int quad = lane >> 4, cl = lane & 15;
#pragma unroll
  for (int mt = 0; mt < 2; mt++) {
#pragma unroll
    for (int nt = 0; nt < 2; nt++) {
      int kp = ktile * 64 + nw * 32 + nt * 16 + cl;
#pragma unroll
      for (int i = 0; i < 4; i++) {
        int q = qtile * 64 + mw * 32 + mt * 16 + quad * 4 + i;
        logit_ws[((size_t)(h * 512 + q)) * 512 + kp] = acc[mt][nt][i];
      }
    }
  }
}

// ---------------- K5: softmax over k with bias + 2D mask ----------------
__global__ __launch_bounds__(256) void k_softmax(
    const float* logit_ws, const float* bias_ws, const int* mask, bf16_t* p_ws) {
  __shared__ float red[8];
  int t = threadIdx.x;
  int hq = blockIdx.x;  // h*512 + q
  int q = hq & 511;
  bool padq = (mask[q] == 0);
  const float* lg = logit_ws + (size_t)hq * 512;
  const float* bi = bias_ws + (size_t)(hq >> 9) * 262144 + (size_t)q * 512;
  int k0 = t * 2;
  float v0 = lg[k0] + bi[k0];
  float v1 = lg[k0 + 1] + bi[k0 + 1];
  if (padq || mask[k0] == 0) v0 = -1e9f;
  if (padq || mask[k0 + 1] == 0) v1 = -1e9f;
  float m = fmaxf(v0, v1);
#pragma unroll
  for (int o = 32; o >= 1; o >>= 1) m = fmaxf(m, __shfl_xor(m, o, 64));
  if ((t & 63) == 0) red[t >> 6] = m;
  __syncthreads();
  m = fmaxf(fmaxf(red[0], red[1]), fmaxf(red[2], red[3]));
  float e0 = __expf(v0 - m), e1 = __expf(v1 - m);
  float s = e0 + e1;
#pragma unroll
  for (int o = 32; o >= 1; o >>= 1) s += __shfl_xor(s, o, 64);
  if ((t & 63) == 0) red[4 + (t >> 6)] = s;
  __syncthreads();
  s = red[4] + red[5] + red[6] + red[7];
  float inv = 1.f / s;
  p_ws[(size_t)hq * 512 + k0] = (bf16_t)(e0 * inv);
  p_ws[(size_t)hq * 512 + k0 + 1] = (bf16_t)(e1 * inv);
}

// ---------------- K6: O = P @ V, * gate -> q-region of qkg ----------------
__global__ __launch_bounds__(256) void k_av(
    const bf16_t* p_ws, const bf16_t* vt, bf16_t* qkg) {
  __shared__ bf16_t Ps[64 * 136];
  __shared__ bf16_t Vs[32 * 136];
  int t = threadIdx.x, lane = t & 63, w = t >> 6;
  // XCD-grouped decode: one head per XCD, qt innermost -> V-tile L2 reuse.
  int j = blockIdx.x;
  int jj = (j & 7) * 2048 + (j >> 3);
  int qt = jj & 7;
  int n = (jj >> 3) & 255;
  int h = jj >> 11;
  f32x4 z = {0.f, 0.f, 0.f, 0.f};
  f32x4 acc[2] = {z, z};
  for (int s = 0; s < 4; s++) {
    int k0 = s * 128;
#pragma unroll
    for (int i = 0; i < 4; i++) {
      int flat = t + i * 256;
      int r = flat >> 4, c8 = flat & 15;
      *(i32x4*)(Ps + r * 136 + c8 * 8) =
          *(const i32x4*)(p_ws + ((size_t)(h * 512 + qt * 64 + r)) * 512 + k0 + c8 * 8);
    }
#pragma unroll
    for (int i = 0; i < 2; i++) {
      int flat = t + i * 256;
      int r = flat >> 4, c8 = flat & 15;  // r = d
      *(i32x4*)(Vs + r * 136 + c8 * 8) =
          *(const i32x4*)(vt + ((size_t)((n * 8 + h) * 32 + r)) * 512 + k0 + c8 * 8);
    }
    __syncthreads();
#pragma unroll
    for (int kk = 0; kk < 128; kk += 32) {
      int ko = kk + (lane >> 4) * 8;
      bf16x8 a = *(const bf16x8*)(Ps + (w * 16 + (lane & 15)) * 136 + ko);
      bf16x8 b0 = *(const bf16x8*)(Vs + ((lane & 15)) * 136 + ko);
      bf16x8 b1 = *(const bf16x8*)(Vs + (16 + (lane & 15)) * 136 + ko);
      acc[0] = mfma16(a, b0, acc[0]);
      acc[1] = mfma16(a, b1, acc[1]);
    }
    __syncthreads();
  }
  int quad = lane >> 4, cl = lane & 15;
#pragma unroll
  for (int nt = 0; nt < 2; nt++) {
#pragma unroll
    for (int i = 0; i < 4; i++) {
      int q = qt * 64 + w * 16 + quad * 4 + i;
      int d = nt * 16 + cl;
      size_t base = ((size_t)(n * 512 + q)) * 768;
      float gate = (float)qkg[base + 512 + h * 32 + d];
      qkg[base + h * 32 + d] = (bf16_t)(acc[nt][i] * gate);
    }
  }
}

// ---------------- K7: out = gated @ w_out + b_out, pad-zeroed ----------------
// Fused over output cols: one block = 64 rows x ALL 256 cols -> A read once.
__global__ __launch_bounds__(256) void k_out(
    const bf16_t* qkg, const bf16_t* wt_out, const void* b_out,
    const int* mask, const int* flag, void* outp) {
  __shared__ bf16_t As[64 * 72];    //  9216 B
  __shared__ bf16_t Bs[256 * 72];   // 36864 B  -> 46 KB total, 3 blocks/CU
  int is32 = *flag;
  int t = threadIdx.x, lane = t & 63, w = t >> 6;
  int row0 = blockIdx.x * 64;
  int hi = lane >> 4, cl = lane & 15;
  f32x4 z = {0.f, 0.f, 0.f, 0.f};
  f32x4 acc[4][4];
#pragma unroll
  for (int m = 0; m < 4; ++m)
#pragma unroll
    for (int n = 0; n < 4; ++n) acc[m][n] = z;
  for (int kt = 0; kt < 4; kt++) {
#pragma unroll
    for (int i = 0; i < 2; i++) {
      int flat = t + i * 256;  // < 512: 64 rows x 8 chunks
      int r = flat >> 3, c8 = flat & 7;
      *(i32x4*)(As + r * 72 + c8 * 8) =
          *(const i32x4*)(qkg + (size_t)(row0 + r) * 768 + kt * 64 + c8 * 8);
    }
#pragma unroll
    for (int i = 0; i < 8; i++) {
      int flat = t + i * 256;  // < 2048: 256 rows x 8 chunks
      int r = flat >> 3, c8 = flat & 7;
      *(i32x4*)(Bs + r * 72 + c8 * 8) =
          *(const i32x4*)(wt_out + (size_t)r * 256 + kt * 64 + c8 * 8);
    }
    __syncthreads();
#pragma unroll
    for (int kk = 0; kk < 64; kk += 32) {
      int ko = kk + hi * 8;
      bf16x8 a[4], b[4];
#pragma unroll
      for (int m = 0; m < 4; ++m)
        a[m] = *(const bf16x8*)(As + (m * 16 + cl) * 72 + ko);
#pragma unroll
      for (int n = 0; n < 4; ++n)
        b[n] = *(const bf16x8*)(Bs + (w * 64 + n * 16 + cl) * 72 + ko);
#pragma unroll
      for (int m = 0; m < 4; ++m)
#pragma unroll
        for (int n = 0; n < 4; ++n) acc[m][n] = mfma16(a[m], b[n], acc[m][n]);
    }
    __syncthreads();
  }
#pragma unroll
  for (int n = 0; n < 4; ++n) {
    int col = w * 64 + n * 16 + cl;
    float bo = ldf(b_out, col, is32);
#pragma unroll
    for (int m = 0; m < 4; ++m) {
#pragma unroll
      for (int i = 0; i < 4; ++i) {
        int r = row0 + m * 16 + hi * 4 + i;
        int l = r & 511;
        float v = acc[m][n][i] + bo;
        if (mask[l] == 0) v = 0.f;
        if (is32) ((float*)outp)[(size_t)r * 256 + col] = v;
        else ((bf16_t*)outp)[(size_t)r * 256 + col] = (bf16_t)v;
      }
    }
  }
}

extern "C" void kernel_launch(void* const* d_in, const int* in_sizes, int n_in,
                              void* d_out, int out_size, void* d_ws, size_t ws_size,
                              hipStream_t stream) {
  const void* msa      = d_in[0];
  const void* pair     = d_in[1];
  const void* ln_msa_g = d_in[2];
  const void* ln_msa_b = d_in[3];
  const void* ln_pair_g= d_in[4];
  const void* ln_pair_b= d_in[5];
  const void* w_q      = d_in[6];
  const void* w_k      = d_in[7];
  const void* w_v      = d_in[8];
  const void* w_b      = d_in[9];
  const void* w_g      = d_in[10];
  const void* b_g      = d_in[11];
  const void* w_out    = d_in[12];
  const void* b_out    = d_in[13];
  const int*  mask     = (const int*)d_in[14];

  char* ws = (char*)d_ws;
  bf16_t* qkg   = (bf16_t*)(ws + OFF_QKG);
  float*  logit = (float*)(ws + OFF_LOG);
  float*  biasb = (float*)(ws + OFF_BIAS);
  bf16_t* pbuf  = (bf16_t*)(ws + OFF_P);
  bf16_t* wtc   = (bf16_t*)(ws + OFF_WT);
  bf16_t* wto   = (bf16_t*)(ws + OFF_WTO);
  int*    flag  = (int*)(ws + OFF_FLAG);
  bf16_t* vt    = (bf16_t*)d_out;            // dead before k_out writes final output
  char*   msaln = (char*)d_out + 67108864u;  // fp32-out case: free until k_out

  k_detect<<<1, 256, 0, stream>>>((const unsigned short*)msa, flag);
  k_transpose<<<1280, 256, 0, stream>>>(w_q, w_k, w_v, w_g, w_out, flag, wtc, wto);
  k_ln<<<2048, 256, 0, stream>>>(msa, ln_msa_g, ln_msa_b, flag, msaln, (char*)qkg);
  k_pair_bias<<<4096, 256, 0, stream>>>(pair, ln_pair_g, ln_pair_b, w_b, flag, biasb);
  k_proj<<<2048, 256, 0, stream>>>(wtc, b_g, mask, flag, msaln, qkg, vt);
  k_logits<<<512, 256, 0, stream>>>(qkg, logit);
  k_softmax<<<4096, 256, 0, stream>>>(logit, biasb, mask, pbuf);
  k_av<<<16384, 256, 0, stream>>>(pbuf, vt, qkg);
  k_out<<<2048, 256, 0, stream>>>(qkg, wto, b_out, mask, flag, d_out);
}

// Round 5
// 752.336 us; speedup vs baseline: 1.3198x; 1.0511x over previous
//
#include <hip/hip_runtime.h>
#include <hip/hip_bf16.h>
#include <math.h>

typedef __bf16 bf16_t;
typedef float f32x4 __attribute__((ext_vector_type(4)));
typedef __bf16 bf16x8 __attribute__((ext_vector_type(8)));
typedef __bf16 bf16x4 __attribute__((ext_vector_type(4)));
typedef int i32x4 __attribute__((ext_vector_type(4)));

#define SCALING 0.17677669529663687f
#define LNEPS 1e-5f

// ws layout (bytes); total = 224,002,176 (vt + msa_ln live in d_out)
#define OFF_QKG   0u            // bf16 [131072][768]: q | k | gate
#define OFF_LOG   201326592u    // f32  [8][512][512]: attn logits (split-K partial 0)
#define OFF_BIAS  209715200u    // f32  [8][512][512]: pair bias (+ split-K partial 1)
#define OFF_P     218103808u    // bf16 [8][512][512]: softmax probs, chunk-XOR swizzled
#define OFF_WT    222298112u    // bf16 [1024][256]  : [wq|wk|wv|wg]^T, K-chunk XOR-swizzled
#define OFF_WTO   222822400u    // bf16 [256][256]   : w_out^T
#define OFF_FLAG  222953472u    // int: 1 if inputs are fp32, 0 if bf16

#define GLOBAL_AS __attribute__((address_space(1)))
#define LDS_AS    __attribute__((address_space(3)))

static __device__ __forceinline__ f32x4 mfma16(bf16x8 a, bf16x8 b, f32x4 c) {
  return __builtin_amdgcn_mfma_f32_16x16x32_bf16(a, b, c, 0, 0, 0);
}

static __device__ __forceinline__ float ldf(const void* p, int i, int is32) {
  return is32 ? ((const float*)p)[i] : (float)((const bf16_t*)p)[i];
}
static __device__ __forceinline__ float scrubf(float x) {
  if (x != x) return 0.f;
  return fminf(fmaxf(x, -3.3e38f), 3.3e38f);
}

// ---------------- K-1: detect input dtype ----------------
__global__ __launch_bounds__(256) void k_detect(const unsigned short* raw, int* flag) {
  __shared__ int s;
  int t = threadIdx.x;
  if (t == 0) s = 0;
  __syncthreads();
  int local = 0;
  for (int i = 0; i < 16; i++) {
    unsigned short u = raw[t * 16 + i];
    int e = (u >> 7) & 0xFF;
    if (e >= 170) local = 1;   // |x| >= 2^43 as bf16: impossible for N(0,1) bf16 data
  }
  if (local) s = 1;
  __syncthreads();
  if (t == 0) *flag = s;
}

// ---------------- K0: transpose weights (any dtype -> bf16) ----------------
// wt_cat: column c's K-row with 16B chunks XOR-swizzled (element k at k ^ ((c&7)<<3))
// so k_proj stages linearly via global_load_lds and reads fragments conflict-free.
__global__ __launch_bounds__(256) void k_transpose(
    const void* wq, const void* wk, const void* wv, const void* wg,
    const void* wout, const int* flag, bf16_t* wt_cat, bf16_t* wt_out) {
  int is32 = *flag;
  int idx = blockIdx.x * 256 + threadIdx.x;
  if (idx < 1024 * 256) {
    int c = idx >> 8, k = idx & 255;
    const void* src = (c < 256) ? wq : (c < 512) ? wk : (c < 768) ? wv : wg;
    wt_cat[c * 256 + (k ^ ((c & 7) << 3))] = (bf16_t)ldf(src, k * 256 + (c & 255), is32);
  } else {
    int i2 = idx - 1024 * 256;  // < 65536
    int c = i2 >> 8, k = i2 & 255;
    wt_out[c * 256 + k] = (bf16_t)ldf(wout, k * 256 + c, is32);
  }
}

// ---------------- K1: msa LayerNorm -> bf16 (dense, chunk-XOR-swizzled) ----------------
__global__ __launch_bounds__(256) void k_ln(
    const void* msa, const void* g, const void* b, const int* flag,
    char* msaln, char* qkg_bytes) {
  int is32 = *flag;
  int t = threadIdx.x, lane = t & 63, w = t >> 6;
  int c0 = lane * 4;
  float gv[4], bv[4];
#pragma unroll
  for (int e = 0; e < 4; e++) { gv[e] = ldf(g, c0 + e, is32); bv[e] = ldf(b, c0 + e, is32); }
  int row0 = blockIdx.x * 64 + w * 16;
  for (int rr = 0; rr < 16; rr++) {
    int r = row0 + rr;
    float x[4];
    if (is32) {
      f32x4 v = *(const f32x4*)((const float*)msa + (size_t)r * 256 + c0);
#pragma unroll
      for (int e = 0; e < 4; e++) x[e] = scrubf(v[e]);
    } else {
      bf16x4 v = *(const bf16x4*)((const bf16_t*)msa + (size_t)r * 256 + c0);
#pragma unroll
      for (int e = 0; e < 4; e++) x[e] = scrubf((float)v[e]);
    }
    float s = x[0] + x[1] + x[2] + x[3];
    float sq = x[0] * x[0] + x[1] * x[1] + x[2] * x[2] + x[3] * x[3];
#pragma unroll
    for (int o = 32; o >= 1; o >>= 1) {
      s += __shfl_xor(s, o, 64);
      sq += __shfl_xor(sq, o, 64);
    }
    float mu = s * (1.f / 256.f);
    float var = sq * (1.f / 256.f) - mu * mu;
    float rs = rsqrtf(fmaxf(var, 0.f) + LNEPS);
    bf16x4 y;
#pragma unroll
    for (int e = 0; e < 4; e++) y[e] = (bf16_t)((x[e] - mu) * rs * gv[e] + bv[e]);
    int pc = (lane >> 1) ^ (r & 7);   // physical 16B chunk within 512B payload
    char* dst = is32 ? (msaln + (size_t)r * 512)
                     : (qkg_bytes + (size_t)r * 1536 + 512);
    *(bf16x4*)(dst + pc * 16 + (lane & 1) * 8) = y;
  }
}

// ---------------- K2: pair LN + @ w_b -> bias[h][q][k] (f32) ----------------
__global__ __launch_bounds__(256) void k_pair_bias(
    const void* pair, const void* g, const void* b,
    const void* wb, const int* flag, float* bias_ws) {
  __shared__ float wbs[128 * 8];  // wb[c][h]
  __shared__ float gs[128], bs[128];
  int is32 = *flag;
  int t = threadIdx.x;
  if (t < 128) { gs[t] = ldf(g, t, is32); bs[t] = ldf(b, t, is32); }
  for (int i = t; i < 1024; i += 256) wbs[i] = ldf(wb, i, is32);
  __syncthreads();
  int lane = t & 63, w = t >> 6;
  int j = lane & 7;        // element-group within row (16 elems each)
  int rowg = lane >> 3;    // row within pass (0..7)
  float gr[16], br[16];
#pragma unroll
  for (int e = 0; e < 16; e++) { gr[e] = gs[j * 16 + e]; br[e] = bs[j * 16 + e]; }
  int row0 = blockIdx.x * 64 + w * 16;
#pragma unroll
  for (int pass = 0; pass < 2; pass++) {
    int row = row0 + pass * 8 + rowg;
    float x[16];
    if (is32) {
#pragma unroll
      for (int i = 0; i < 4; i++) {
        f32x4 v = *(const f32x4*)((const float*)pair + (size_t)row * 128 + j * 16 + i * 4);
#pragma unroll
        for (int e = 0; e < 4; e++) x[i * 4 + e] = scrubf(v[e]);
      }
    } else {
#pragma unroll
      for (int i = 0; i < 2; i++) {
        i32x4 raw = *(const i32x4*)((const bf16_t*)pair + (size_t)row * 128 + j * 16 + i * 8);
        const bf16_t* sp = (const bf16_t*)&raw;
#pragma unroll
        for (int e = 0; e < 8; e++) x[i * 8 + e] = scrubf((float)sp[e]);
      }
    }
    float s = 0.f, sq = 0.f;
#pragma unroll
    for (int e = 0; e < 16; e++) { s += x[e]; sq += x[e] * x[e]; }
#pragma unroll
    for (int o = 1; o <= 4; o <<= 1) {
      s += __shfl_xor(s, o, 64);
      sq += __shfl_xor(sq, o, 64);
    }
    float mu = s * (1.f / 128.f);
    float var = sq * (1.f / 128.f) - mu * mu;
    float rs = rsqrtf(fmaxf(var, 0.f) + LNEPS);
    float ph[8] = {0.f, 0.f, 0.f, 0.f, 0.f, 0.f, 0.f, 0.f};
#pragma unroll
    for (int e = 0; e < 16; e++) {
      float xn = (x[e] - mu) * rs * gr[e] + br[e];
      const float* wp = wbs + (j * 16 + e) * 8;
      f32x4 w0 = *(const f32x4*)wp;
      f32x4 w1 = *(const f32x4*)(wp + 4);
#pragma unroll
      for (int hh = 0; hh < 4; hh++) { ph[hh] += xn * w0[hh]; ph[4 + hh] += xn * w1[hh]; }
    }
#pragma unroll
    for (int o = 1; o <= 4; o <<= 1) {
#pragma unroll
      for (int hh = 0; hh < 8; hh++) ph[hh] += __shfl_xor(ph[hh], o, 64);
    }
    if (j == 0) {
      int qp = row >> 9, kp = row & 511;
      float* bp = bias_ws + (size_t)qp * 512 + kp;
#pragma unroll
      for (int hh = 0; hh < 8; hh++) bp[(size_t)hh * 262144] = ph[hh];
    }
  }
}

// ---------------- K3: QKVG projection GEMM ----------------
// 2048 blocks x 256 threads, LDS 64KB -> 2 blocks/CU. A frags hoisted to 128
// VGPRs; B half-tiles double-buffered via global_load_lds.
static __device__ __forceinline__ void issue_b(const bf16_t* wtc, int col0, int half,
                                               char* dst, int t) {
#pragma unroll
  for (int j = 0; j < 8; ++j) {
    int o = t * 16 + j * 4096;           // 0..32752
    int row = o >> 8, within = o & 255;  // 256 B per half-row
    const char* src = (const char*)wtc + (size_t)(col0 + row) * 512 + half * 256 + within;
    __builtin_amdgcn_global_load_lds((const GLOBAL_AS void*)src,
                                     (LDS_AS void*)(dst + o), 16, 0, 0);
  }
}

__global__ __launch_bounds__(256, 2) void k_proj(
    const bf16_t* wt_cat, const void* bg, const int* mask, const int* flag,
    const char* msaln, bf16_t* qkg, bf16_t* vt) {
  __shared__ __align__(16) char lds[65536];
  char* B0 = lds + 32768;            // B half-tile [128 cols][128 K] bf16 = 32KB
  char* B1 = lds;                    // overlaps A region (dead after frag hoist)
  int is32 = *flag;
  int t = threadIdx.x, lane = t & 63, wc = t >> 6;   // 4 waves; wave = 64 rows x 32 cols
  int hi = lane >> 4, cl = lane & 15;
  int row0 = blockIdx.x * 64;
  int rbase = row0 + hi * 4;

  // prologue scalar loads
  unsigned padbits = 0;
#pragma unroll
  for (int m = 0; m < 4; ++m)
#pragma unroll
    for (int i = 0; i < 4; ++i)
      if (mask[(rbase + m * 16 + i) & 511] == 0) padbits |= 1u << (m * 4 + i);
  float bgv[2][2];
#pragma unroll
  for (int bb = 0; bb < 2; ++bb)
#pragma unroll
    for (int n = 0; n < 2; ++n)
      bgv[bb][n] = ldf(bg, bb * 128 + wc * 32 + n * 16 + cl, is32);

  // stage A tile (64 rows x 512B, pre-LN'd bf16, chunk-swizzled at source)
  {
    const char* abase = is32 ? msaln : ((const char*)qkg + 512);
    size_t astride = is32 ? 512 : 1536;
#pragma unroll
    for (int j = 0; j < 8; ++j) {
      int o = t * 16 + j * 4096;
      int row = o >> 9, within = o & 511;
      const char* src = abase + (size_t)(row0 + row) * astride + within;
      __builtin_amdgcn_global_load_lds((const GLOBAL_AS void*)src,
                                       (LDS_AS void*)(lds + o), 16, 0, 0);
    }
  }
  issue_b(wt_cat, 0, 0, B0, t);      // bn0 half0
  __syncthreads();                   // A + h0 landed

  // one-shot A fragment hoist (swizzled chunks -> conflict-free ds_read_b128)
  bf16x8 aall[8][4];
#pragma unroll
  for (int ks = 0; ks < 8; ++ks)
#pragma unroll
    for (int m = 0; m < 4; ++m)
      aall[ks][m] = *(const bf16x8*)(lds + (size_t)(cl + m * 16) * 512 +
                                     (((ks * 4 + hi) ^ (cl & 7)) << 4));
  __syncthreads();                   // all frag reads done; B1 region free

  int brow0 = wc * 32 + cl, brow1 = brow0 + 16;
  int sb = (cl & 7) << 4;
  f32x4 z = {0.f, 0.f, 0.f, 0.f};
  f32x4 acc[4][2] = {{z, z}, {z, z}, {z, z}, {z, z}};

  for (int bn = 0; bn < 8; ++bn) {
    issue_b(wt_cat, bn << 7, 1, B1, t);   // this bn's half1
#pragma unroll
    for (int kk = 0; kk < 4; ++kk) {      // half0 from B0 (ks 0..3)
      int k8 = (kk * 4 + hi) << 4;
      bf16x8 b0 = *(const bf16x8*)(B0 + brow0 * 256 + (k8 ^ sb));
      bf16x8 b1 = *(const bf16x8*)(B0 + brow1 * 256 + (k8 ^ sb));
#pragma unroll
      for (int m = 0; m < 4; ++m) {
        acc[m][0] = mfma16(aall[kk][m], b0, acc[m][0]);
        acc[m][1] = mfma16(aall[kk][m], b1, acc[m][1]);
      }
    }
    __syncthreads();                      // h1 landed; B0 free
    if (bn < 7) issue_b(wt_cat, (bn + 1) << 7, 0, B0, t);  // next bn's half0
#pragma unroll
    for (int kk = 0; kk < 4; ++kk) {      // half1 from B1 (ks 4..7)
      int k8 = (kk * 4 + hi) << 4;
      bf16x8 b0 = *(const bf16x8*)(B1 + brow0 * 256 + (k8 ^ sb));
      bf16x8 b1 = *(const bf16x8*)(B1 + brow1 * 256 + (k8 ^ sb));
#pragma unroll
      for (int m = 0; m < 4; ++m) {
        acc[m][0] = mfma16(aall[4 + kk][m], b0, acc[m][0]);
        acc[m][1] = mfma16(aall[4 + kk][m], b1, acc[m][1]);
      }
    }
    __syncthreads();                      // next h0 landed; B1 free
    // epilogue for bn (stores drain under next bn's work until its barrier)
    int region = bn >> 1, col0 = bn << 7;
    if (region == 2) {
      // vt store, chunk-XOR swizzled (chunk l>>3 at (l>>3)^(d&7)) for k_av
#pragma unroll
      for (int m = 0; m < 4; ++m) {
#pragma unroll
        for (int n = 0; n < 2; ++n) {
          int col = col0 + wc * 32 + n * 16 + cl;
          int hd = col & 255;
          int d = hd & 31;
          int rb = rbase + m * 16;
          int l = rb & 511;
          bf16x4 y;
#pragma unroll
          for (int i = 0; i < 4; ++i)
            y[i] = (bf16_t)(((padbits >> (m * 4 + i)) & 1) ? 0.f : acc[m][n][i]);
          *(bf16x4*)((char*)vt +
                     ((size_t)((rb >> 9) * 8 + (hd >> 5)) * 32 + d) * 1024 +
                     (((l >> 3) ^ (d & 7)) << 4) + ((l & 7) << 1)) = y;
          acc[m][n] = z;
        }
      }
    } else {
#pragma unroll
      for (int m = 0; m < 4; ++m) {
#pragma unroll
        for (int n = 0; n < 2; ++n) {
          int col = col0 + wc * 32 + n * 16 + cl;
#pragma unroll
          for (int i = 0; i < 4; ++i) {
            int r = rbase + m * 16 + i;
            bool pad = (padbits >> (m * 4 + i)) & 1;
            float v = acc[m][n][i];
            if (region == 0) {
              qkg[(size_t)r * 768 + col] = (bf16_t)(pad ? 0.f : v);
            } else if (region == 1) {
              qkg[(size_t)r * 768 + col] = (bf16_t)(pad ? 0.f : v * SCALING);
            } else {
              float xg = v + bgv[bn & 1][n];
              qkg[(size_t)r * 768 + 512 + (col & 255)] = (bf16_t)(1.f / (1.f + __expf(-xg)));
            }
          }
          acc[m][n] = z;
        }
      }
    }
  }
}

// ---------------- K4: logits[h][q][k] = sum_{n,d} q*k, split-K over n ----------------
// 256 blocks x 512 thr: (h, qt, kt, ks). Tile 128q x 128k, K=4096 (128 n) each.
// ks=0 writes logit_ws; ks=1 ACCUMULATES into bias_ws (bias + partial1) so
// k_softmax's logit+bias sum yields the full K=8192 reduction -- no atomics,
// no extra buffer, idempotent across launches (k_pair_bias rewrites bias fresh).
__global__ __launch_bounds__(512) void k_logits(
    const bf16_t* qkg, float* logit_ws, float* bias_ws) {
  __shared__ __align__(16) char lds[131072];
  int t = threadIdx.x, lane = t & 63, w = t >> 6;
  int j = blockIdx.x;
  int h = j & 7, rest = j >> 3;           // same h -> same XCD
  int kt = rest & 3, qt = (rest >> 2) & 3, ks = rest >> 4;
  int qw = w >> 2, kw = w & 3;            // wave tile: 64q x 32k
  int hi = lane >> 4, cl = lane & 15;
  int q0 = qt * 128, k0 = kt * 128;

  auto issue = [&](int step, char* buf) {
    int n0 = ks * 128 + step * 4;
#pragma unroll
    for (int jj = 0; jj < 4; ++jj) {      // A (q-region)
      int o = t * 16 + jj * 8192;
      int r = o >> 8, p = (o & 255) >> 4;
      int l = p ^ (r & 7);
      const char* src = (const char*)qkg +
          ((size_t)(n0 + (l >> 2)) * 512 + q0 + r) * 1536 + h * 64 + (l & 3) * 16;
      __builtin_amdgcn_global_load_lds((const GLOBAL_AS void*)src,
                                       (LDS_AS void*)(buf + o), 16, 0, 0);
    }
#pragma unroll
    for (int jj = 0; jj < 4; ++jj) {      // B (k-region: +512B in row)
      int o = t * 16 + jj * 8192;
      int r = o >> 8, p = (o & 255) >> 4;
      int l = p ^ (r & 7);
      const char* src = (const char*)qkg +
          ((size_t)(n0 + (l >> 2)) * 512 + k0 + r) * 1536 + 512 + h * 64 + (l & 3) * 16;
      __builtin_amdgcn_global_load_lds((const GLOBAL_AS void*)src,
                                       (LDS_AS void*)(buf + 32768 + o), 16, 0, 0);
    }
  };

  f32x4 z = {0.f, 0.f, 0.f, 0.f};
  f32x4 acc[4][2] = {{z, z}, {z, z}, {z, z}, {z, z}};
  issue(0, lds);
  __syncthreads();
  for (int step = 0; step < 32; ++step) {
    char* buf = lds + (step & 1) * 65536;
    if (step < 31) issue(step + 1, lds + ((step + 1) & 1) * 65536);
    char* Ab = buf;
    char* Bb = buf + 32768;
#pragma unroll
    for (int ku = 0; ku < 4; ++ku) {
      int ch = ((ku * 4 + hi) ^ (cl & 7)) << 4;
      bf16x8 a[4], b[2];
#pragma unroll
      for (int m = 0; m < 4; ++m)
        a[m] = *(const bf16x8*)(Ab + (qw * 64 + m * 16 + cl) * 256 + ch);
#pragma unroll
      for (int n = 0; n < 2; ++n)
        b[n] = *(const bf16x8*)(Bb + (kw * 32 + n * 16 + cl) * 256 + ch);
#pragma unroll
      for (int m = 0; m < 4; ++m)
#pragma unroll
        for (int n = 0; n < 2; ++n) acc[m][n] = mfma16(a[m], b[n], acc[m][n]);
    }
    __syncthreads();
  }
#pragma unroll
  for (int m = 0; m < 4; ++m) {
#pragma unroll
    for (int n = 0; n < 2; ++n) {
      int k = k0 + kw * 32 + n * 16 + cl;
#pragma unroll
      for (int i = 0; i < 4; ++i) {
        int q = q0 + qw * 64 + m * 16 + hi * 4 + i;
        size_t idx = ((size_t)(h * 512 + q)) * 512 + k;
        if (ks == 0) logit_ws[idx] = acc[m][n][i];
        else bias_ws[idx] += acc[m][n][i];
      }
    }
  }
}

// ---------------- K5: softmax over k with bias + 2D mask ----------------
// P store is chunk-XOR swizzled (chunk (k>>3) at (k>>3)^(q&7)) for k_av's hoist.
__global__ __launch_bounds__(256) void k_softmax(
    const float* logit_ws, const float* bias_ws, const int* mask, bf16_t* p_ws) {
  __shared__ float red[8];
  int t = threadIdx.x;
  int hq = blockIdx.x;  // h*512 + q
  int q = hq & 511;
  bool padq = (mask[q] == 0);
  const float* lg = logit_ws + (size_t)hq * 512;
  const float* bi = bias_ws + (size_t)(hq >> 9) * 262144 + (size_t)q * 512;
  int k0 = t * 2;
  float v0 = lg[k0] + bi[k0];
  float v1 = lg[k0 + 1] + bi[k0 + 1];
  if (padq || mask[k0] == 0) v0 = -1e9f;
  if (padq || mask[k0 + 1] == 0) v1 = -1e9f;
  float m = fmaxf(v0, v1);
#pragma unroll
  for (int o = 32; o >= 1; o >>= 1) m = fmaxf(m, __shfl_xor(m, o, 64));
  if ((t & 63) == 0) red[t >> 6] = m;
  __syncthreads();
  m = fmaxf(fmaxf(red[0], red[1]), fmaxf(red[2], red[3]));
  float e0 = __expf(v0 - m), e1 = __expf(v1 - m);
  float s = e0 + e1;
#pragma unroll
  for (int o = 32; o >= 1; o >>= 1) s += __shfl_xor(s, o, 64);
  if ((t & 63) == 0) red[4 + (t >> 6)] = s;
  __syncthreads();
  s = red[4] + red[5] + red[6] + red[7];
  float inv = 1.f / s;
  int chunk = (t >> 2) ^ (q & 7);
  bf16_t* pp = (bf16_t*)((char*)p_ws + (size_t)hq * 1024 + chunk * 16 + (t & 3) * 4);
  pp[0] = (bf16_t)(e0 * inv);
  pp[1] = (bf16_t)(e1 * inv);
}

// ---------------- K6: O = P @ V, * gate -> q-region of qkg ----------------
// 512 blocks x 512 thr: (h, qt[128 q-rows], ng[16 n]). P hoisted to 64 VGPRs/lane
// once; V[n] (32KB) double-buffered via global_load_lds. vt & p_ws chunk-XOR
// swizzled at producers -> all ds_read_b128 conflict-free.
__global__ __launch_bounds__(512, 2) void k_av(
    const bf16_t* p_ws, const bf16_t* vt, bf16_t* qkg) {
  __shared__ __align__(16) char lds[65536];
  int t = threadIdx.x, lane = t & 63, w = t >> 6;   // 8 waves, wave = 16 q-rows
  int hi = lane >> 4, cl = lane & 15;
  int j = blockIdx.x;
  int h = j & 7, rest = j >> 3;       // same h -> same XCD
  int ng = rest >> 2, qt = rest & 3;  // qt innermost -> V-group L2 reuse
  int q0 = qt * 128;

  const char* pbase = (const char*)p_ws + ((size_t)h * 512 + q0) * 1024;
  bf16x8 pf[16];
  // phase 1: stage P rows 0..63, waves 0-3 hoist their 16 rows
#pragma unroll
  for (int jj = 0; jj < 8; ++jj) {
    int o = t * 16 + jj * 8192;
    __builtin_amdgcn_global_load_lds((const GLOBAL_AS void*)(pbase + o),
                                     (LDS_AS void*)(lds + o), 16, 0, 0);
  }
  __syncthreads();
  if (w < 4) {
    int lr = w * 16 + cl;
#pragma unroll
    for (int ks = 0; ks < 16; ++ks)
      pf[ks] = *(const bf16x8*)(lds + lr * 1024 + (((ks * 4 + hi) ^ (cl & 7)) << 4));
  }
  __syncthreads();
  // phase 2: rows 64..127, waves 4-7 hoist
#pragma unroll
  for (int jj = 0; jj < 8; ++jj) {
    int o = t * 16 + jj * 8192;
    __builtin_amdgcn_global_load_lds((const GLOBAL_AS void*)(pbase + 65536 + o),
                                     (LDS_AS void*)(lds + o), 16, 0, 0);
  }
  __syncthreads();
  if (w >= 4) {
    int lr = (w - 4) * 16 + cl;
#pragma unroll
    for (int ks = 0; ks < 16; ++ks)
      pf[ks] = *(const bf16x8*)(lds + lr * 1024 + (((ks * 4 + hi) ^ (cl & 7)) << 4));
  }
  __syncthreads();

  char* V0 = lds;
  char* V1 = lds + 32768;
  auto issue_v = [&](int nn, char* dst) {
    const char* src = (const char*)vt + ((size_t)((ng * 16 + nn) * 8 + h) * 32) * 1024;
#pragma unroll
    for (int jj = 0; jj < 4; ++jj) {
      int o = t * 16 + jj * 8192;
      __builtin_amdgcn_global_load_lds((const GLOBAL_AS void*)(src + o),
                                       (LDS_AS void*)(dst + o), 16, 0, 0);
    }
  };
  issue_v(0, V0);
  __syncthreads();
  int Lb = q0 + w * 16 + hi * 4;
  f32x4 z = {0.f, 0.f, 0.f, 0.f};
  for (int nn = 0; nn < 16; ++nn) {
    char* cur = (nn & 1) ? V1 : V0;
    if (nn < 15) issue_v(nn + 1, (nn & 1) ? V0 : V1);
    f32x4 a0 = z, a1 = z;
#pragma unroll
    for (int ks = 0; ks < 16; ++ks) {
      int ch = ((ks * 4 + hi) ^ (cl & 7)) << 4;
      bf16x8 b0 = *(const bf16x8*)(cur + cl * 1024 + ch);
      bf16x8 b1 = *(const bf16x8*)(cur + (16 + cl) * 1024 + ch);
      a0 = mfma16(pf[ks], b0, a0);
      a1 = mfma16(pf[ks], b1, a1);
    }
    int n = ng * 16 + nn;
#pragma unroll
    for (int i = 0; i < 4; ++i) {
      size_t base = ((size_t)n * 512 + Lb + i) * 768 + h * 32 + cl;
      float g0 = (float)qkg[base + 512];
      float g1 = (float)qkg[base + 512 + 16];
      qkg[base] = (bf16_t)(a0[i] * g0);
      qkg[base + 16] = (bf16_t)(a1[i] * g1);
    }
    __syncthreads();
  }
}

// ---------------- K7: out = gated @ w_out + b_out, pad-zeroed ----------------
// Fused over output cols: one block = 64 rows x ALL 256 cols -> A read once.
__global__ __launch_bounds__(256) void k_out(
    const bf16_t* qkg, const bf16_t* wt_out, const void* b_out,
    const int* mask, const int* flag, void* outp) {
  __shared__ bf16_t As[64 * 72];    //  9216 B
  __shared__ bf16_t Bs[256 * 72];   // 36864 B  -> 46 KB total, 3 blocks/CU
  int is32 = *flag;
  int t = threadIdx.x, lane = t & 63, w = t >> 6;
  int row0 = blockIdx.x * 64;
  int hi = lane >> 4, cl = lane & 15;
  f32x4 z = {0.f, 0.f, 0.f, 0.f};
  f32x4 acc[4][4];
#pragma unroll
  for (int m = 0; m < 4; ++m)
#pragma unroll
    for (int n = 0; n < 4; ++n) acc[m][n] = z;
  for (int kt = 0; kt < 4; kt++) {
#pragma unroll
    for (int i = 0; i < 2; i++) {
      int flat = t + i * 256;  // < 512: 64 rows x 8 chunks
      int r = flat >> 3, c8 = flat & 7;
      *(i32x4*)(As + r * 72 + c8 * 8) =
          *(const i32x4*)(qkg + (size_t)(row0 + r) * 768 + kt * 64 + c8 * 8);
    }
#pragma unroll
    for (int i = 0; i < 8; i++) {
      int flat = t + i * 256;  // < 2048: 256 rows x 8 chunks
      int r = flat >> 3, c8 = flat & 7;
      *(i32x4*)(Bs + r * 72 + c8 * 8) =
          *(const i32x4*)(wt_out + (size_t)r * 256 + kt * 64 + c8 * 8);
    }
    __syncthreads();
#pragma unroll
    for (int kk = 0; kk < 64; kk += 32) {
      int ko = kk + hi * 8;
      bf16x8 a[4], b[4];
#pragma unroll
      for (int m = 0; m < 4; ++m)
        a[m] = *(const bf16x8*)(As + (m * 16 + cl) * 72 + ko);
#pragma unroll
      for (int n = 0; n < 4; ++n)
        b[n] = *(const bf16x8*)(Bs + (w * 64 + n * 16 + cl) * 72 + ko);
#pragma unroll
      for (int m = 0; m < 4; ++m)
#pragma unroll
        for (int n = 0; n < 4; ++n) acc[m][n] = mfma16(a[m], b[n], acc[m][n]);
    }
    __syncthreads();
  }
#pragma unroll
  for (int n = 0; n < 4; ++n) {
    int col = w * 64 + n * 16 + cl;
    float bo = ldf(b_out, col, is32);
#pragma unroll
    for (int m = 0; m < 4; ++m) {
#pragma unroll
      for (int i = 0; i < 4; ++i) {
        int r = row0 + m * 16 + hi * 4 + i;
        int l = r & 511;
        float v = acc[m][n][i] + bo;
        if (mask[l] == 0) v = 0.f;
        if (is32) ((float*)outp)[(size_t)r * 256 + col] = v;
        else ((bf16_t*)outp)[(size_t)r * 256 + col] = (bf16_t)v;
      }
    }
  }
}

extern "C" void kernel_launch(void* const* d_in, const int* in_sizes, int n_in,
                              void* d_out, int out_size, void* d_ws, size_t ws_size,
                              hipStream_t stream) {
  const void* msa      = d_in[0];
  const void* pair     = d_in[1];
  const void* ln_msa_g = d_in[2];
  const void* ln_msa_b = d_in[3];
  const void* ln_pair_g= d_in[4];
  const void* ln_pair_b= d_in[5];
  const void* w_q      = d_in[6];
  const void* w_k      = d_in[7];
  const void* w_v      = d_in[8];
  const void* w_b      = d_in[9];
  const void* w_g      = d_in[10];
  const void* b_g      = d_in[11];
  const void* w_out    = d_in[12];
  const void* b_out    = d_in[13];
  const int*  mask     = (const int*)d_in[14];

  char* ws = (char*)d_ws;
  bf16_t* qkg   = (bf16_t*)(ws + OFF_QKG);
  float*  logit = (float*)(ws + OFF_LOG);
  float*  biasb = (float*)(ws + OFF_BIAS);
  bf16_t* pbuf  = (bf16_t*)(ws + OFF_P);
  bf16_t* wtc   = (bf16_t*)(ws + OFF_WT);
  bf16_t* wto   = (bf16_t*)(ws + OFF_WTO);
  int*    flag  = (int*)(ws + OFF_FLAG);
  bf16_t* vt    = (bf16_t*)d_out;            // dead before k_out writes final output
  char*   msaln = (char*)d_out + 67108864u;  // fp32-out case: free until k_out

  k_detect<<<1, 256, 0, stream>>>((const unsigned short*)msa, flag);
  k_transpose<<<1280, 256, 0, stream>>>(w_q, w_k, w_v, w_g, w_out, flag, wtc, wto);
  k_ln<<<2048, 256, 0, stream>>>(msa, ln_msa_g, ln_msa_b, flag, msaln, (char*)qkg);
  k_pair_bias<<<4096, 256, 0, stream>>>(pair, ln_pair_g, ln_pair_b, w_b, flag, biasb);
  k_proj<<<2048, 256, 0, stream>>>(wtc, b_g, mask, flag, msaln, qkg, vt);
  k_logits<<<256, 512, 0, stream>>>(qkg, logit, biasb);
  k_softmax<<<4096, 256, 0, stream>>>(logit, biasb, mask, pbuf);
  k_av<<<512, 512, 0, stream>>>(pbuf, vt, qkg);
  k_out<<<2048, 256, 0, stream>>>(qkg, wto, b_out, mask, flag, d_out);
}